// Round 1
// baseline (27476.776 us; speedup 1.0000x reference)
//
#include <hip/hip_runtime.h>
#include <math.h>

// Problem constants
#define TT 256      // sequence length
#define BB 64       // batch
#define DD 300      // embedding dim
#define HH 256      // hidden
#define KK 37       // CRF states
#define FH 1024     // 4*H
#define MTOT (TT*BB) // 16384 rows, time-major r = t*64 + b

// ---------- bf16 helpers (storage format for intermediates) ----------
__device__ __forceinline__ float bf2f(unsigned short u) {
    union { float f; unsigned int i; } v; v.i = ((unsigned int)u) << 16; return v.f;
}
__device__ __forceinline__ unsigned short f2bf(float f) {
    union { float f; unsigned int i; } v; v.f = f;
    unsigned int i = v.i;
    unsigned int r = (i + 0x7FFFu + ((i >> 16) & 1u)) >> 16; // RNE
    return (unsigned short)r;
}
__device__ __forceinline__ float sigm(float x)   { return 1.0f / (1.0f + __expf(-x)); }
__device__ __forceinline__ float tanh_f(float x) { return 2.0f / (1.0f + __expf(-2.0f * x)) - 1.0f; }

// ---------- GEMM 1: zin0 = gather(emb, text) @ Wih0^T + b0  (both dirs) ----------
// M=16384 (r=t*64+b), N=1024, K=300. Output bf16 (T,B,1024).
__global__ __launch_bounds__(256) void gemm_embed(
    const int* __restrict__ text, const float* __restrict__ emb,
    const float* __restrict__ Wf, const float* __restrict__ bf_,
    const float* __restrict__ Wb, const float* __restrict__ bb_,
    unsigned short* __restrict__ zf, unsigned short* __restrict__ zb)
{
    const int dir = blockIdx.z;
    const float* W    = dir ? Wb  : Wf;
    const float* bias = dir ? bb_ : bf_;
    unsigned short* out = dir ? zb : zf;

    __shared__ float As[16][65];
    __shared__ float Bs[16][65];

    const int bm = blockIdx.x * 64;
    const int bn = blockIdx.y * 64;
    const int tid = threadIdx.x;
    const int ml = tid >> 2;          // 0..63 (row within tile)
    const int kl = (tid & 3) * 4;     // 0,4,8,12

    const int r = bm + ml;
    const int t = r >> 6, b = r & 63;
    const int idx = text[b * TT + t];
    const float* arow = emb + idx * DD;
    const float* brow = W + (bn + ml) * DD;

    const int tx4 = (tid & 15) * 4, ty4 = (tid >> 4) * 4;
    float acc[4][4] = {};

    for (int kk = 0; kk < DD; kk += 16) {
        float4 av = make_float4(0.f, 0.f, 0.f, 0.f);
        float4 bv = make_float4(0.f, 0.f, 0.f, 0.f);
        const int d = kk + kl;
        if (d + 3 < DD) {            // DD % 4 == 0 -> no partial vectors
            av = *(const float4*)(arow + d);
            bv = *(const float4*)(brow + d);
        }
        As[kl + 0][ml] = av.x; As[kl + 1][ml] = av.y; As[kl + 2][ml] = av.z; As[kl + 3][ml] = av.w;
        Bs[kl + 0][ml] = bv.x; Bs[kl + 1][ml] = bv.y; Bs[kl + 2][ml] = bv.z; Bs[kl + 3][ml] = bv.w;
        __syncthreads();
        #pragma unroll
        for (int k = 0; k < 16; k++) {
            float a0 = As[k][ty4 + 0], a1 = As[k][ty4 + 1], a2 = As[k][ty4 + 2], a3 = As[k][ty4 + 3];
            float b0 = Bs[k][tx4 + 0], b1 = Bs[k][tx4 + 1], b2 = Bs[k][tx4 + 2], b3 = Bs[k][tx4 + 3];
            acc[0][0] += a0*b0; acc[0][1] += a0*b1; acc[0][2] += a0*b2; acc[0][3] += a0*b3;
            acc[1][0] += a1*b0; acc[1][1] += a1*b1; acc[1][2] += a1*b2; acc[1][3] += a1*b3;
            acc[2][0] += a2*b0; acc[2][1] += a2*b1; acc[2][2] += a2*b2; acc[2][3] += a2*b3;
            acc[3][0] += a3*b0; acc[3][1] += a3*b1; acc[3][2] += a3*b2; acc[3][3] += a3*b3;
        }
        __syncthreads();
    }
    #pragma unroll
    for (int i = 0; i < 4; i++) {
        const int rr = bm + ty4 + i;
        #pragma unroll
        for (int jj = 0; jj < 4; jj++) {
            const int nn = bn + tx4 + jj;
            out[rr * FH + nn] = f2bf(acc[i][jj] + bias[nn]);
        }
    }
}

// ---------- GEMM 2: zin1 = h0 @ Wih1^T + b1 (both dirs). A is bf16, K=512 ----------
__global__ __launch_bounds__(256) void gemm_h(
    const unsigned short* __restrict__ h0,
    const float* __restrict__ Wf, const float* __restrict__ bf_,
    const float* __restrict__ Wb, const float* __restrict__ bb_,
    unsigned short* __restrict__ zf, unsigned short* __restrict__ zb)
{
    const int dir = blockIdx.z;
    const float* W    = dir ? Wb  : Wf;
    const float* bias = dir ? bb_ : bf_;
    unsigned short* out = dir ? zb : zf;

    __shared__ float As[16][65];
    __shared__ float Bs[16][65];

    const int bm = blockIdx.x * 64;
    const int bn = blockIdx.y * 64;
    const int tid = threadIdx.x;
    const int ml = tid >> 2;
    const int kl = (tid & 3) * 4;

    const unsigned short* arow = h0 + (bm + ml) * 512;
    const float* brow = W + (bn + ml) * 512;

    const int tx4 = (tid & 15) * 4, ty4 = (tid >> 4) * 4;
    float acc[4][4] = {};

    for (int kk = 0; kk < 512; kk += 16) {
        const int d = kk + kl;
        ushort4 av4 = *(const ushort4*)(arow + d);
        float4  bv  = *(const float4*)(brow + d);
        As[kl + 0][ml] = bf2f(av4.x); As[kl + 1][ml] = bf2f(av4.y);
        As[kl + 2][ml] = bf2f(av4.z); As[kl + 3][ml] = bf2f(av4.w);
        Bs[kl + 0][ml] = bv.x; Bs[kl + 1][ml] = bv.y; Bs[kl + 2][ml] = bv.z; Bs[kl + 3][ml] = bv.w;
        __syncthreads();
        #pragma unroll
        for (int k = 0; k < 16; k++) {
            float a0 = As[k][ty4 + 0], a1 = As[k][ty4 + 1], a2 = As[k][ty4 + 2], a3 = As[k][ty4 + 3];
            float b0 = Bs[k][tx4 + 0], b1 = Bs[k][tx4 + 1], b2 = Bs[k][tx4 + 2], b3 = Bs[k][tx4 + 3];
            acc[0][0] += a0*b0; acc[0][1] += a0*b1; acc[0][2] += a0*b2; acc[0][3] += a0*b3;
            acc[1][0] += a1*b0; acc[1][1] += a1*b1; acc[1][2] += a1*b2; acc[1][3] += a1*b3;
            acc[2][0] += a2*b0; acc[2][1] += a2*b1; acc[2][2] += a2*b2; acc[2][3] += a2*b3;
            acc[3][0] += a3*b0; acc[3][1] += a3*b1; acc[3][2] += a3*b2; acc[3][3] += a3*b3;
        }
        __syncthreads();
    }
    #pragma unroll
    for (int i = 0; i < 4; i++) {
        const int rr = bm + ty4 + i;
        #pragma unroll
        for (int jj = 0; jj < 4; jj++) {
            const int nn = bn + tx4 + jj;
            out[rr * FH + nn] = f2bf(acc[i][jj] + bias[nn]);
        }
    }
}

// ---------- LSTM recurrence: grid (16 batch-groups, 2 dirs), 128 threads ----------
// Each block: 4 batches. Thread j owns hidden units j and j+128 (all 4 gates):
// 8 Whh rows/thread -> 32 FMA per LDS h read. h double-buffered in LDS (f32).
__global__ __launch_bounds__(128) void lstm_kernel(
    const unsigned short* __restrict__ zin_f, const unsigned short* __restrict__ zin_b,
    const float* __restrict__ Whh_f, const float* __restrict__ Whh_b,
    unsigned short* __restrict__ h_out)  // (T,B,512) bf16; fwd->cols[0:256), bwd->[256:512)
{
    const int dir = blockIdx.y;
    const unsigned short* zin = dir ? zin_b : zin_f;
    const float* Whh = dir ? Whh_b : Whh_f;
    const int off = dir ? HH : 0;

    const int bg = blockIdx.x * 4;
    const int j = threadIdx.x;

    __shared__ float hs[2][4][HH];
    for (int x = j; x < 2 * 4 * HH; x += 128) ((float*)hs)[x] = 0.0f;
    __syncthreads();

    float c[2][4] = {};
    int cur = 0;

    const float* wr[8];
    #pragma unroll
    for (int g = 0; g < 4; g++) {
        wr[g]     = Whh + (g * HH + j) * HH;
        wr[4 + g] = Whh + (g * HH + j + 128) * HH;
    }

    for (int ts = 0; ts < TT; ts++) {
        const int tt = dir ? (TT - 1 - ts) : ts;
        float acc[8][4] = {};
        #pragma unroll 4
        for (int k4 = 0; k4 < HH / 4; k4++) {
            float4 h4[4];
            #pragma unroll
            for (int bb = 0; bb < 4; bb++)
                h4[bb] = *(const float4*)&hs[cur][bb][k4 * 4];
            #pragma unroll
            for (int rI = 0; rI < 8; rI++) {
                const float4 w = *(const float4*)(wr[rI] + k4 * 4);
                #pragma unroll
                for (int bb = 0; bb < 4; bb++)
                    acc[rI][bb] += w.x * h4[bb].x + w.y * h4[bb].y + w.z * h4[bb].z + w.w * h4[bb].w;
            }
        }
        #pragma unroll
        for (int uu = 0; uu < 2; uu++) {
            const int u = j + uu * 128;
            #pragma unroll
            for (int bb = 0; bb < 4; bb++) {
                const int base = (tt * BB + bg + bb) * FH;
                const float zi  = acc[uu * 4 + 0][bb] + bf2f(zin[base + 0 * HH + u]);
                const float zf_ = acc[uu * 4 + 1][bb] + bf2f(zin[base + 1 * HH + u]);
                const float zg  = acc[uu * 4 + 2][bb] + bf2f(zin[base + 2 * HH + u]);
                const float zo  = acc[uu * 4 + 3][bb] + bf2f(zin[base + 3 * HH + u]);
                const float cc = sigm(zf_) * c[uu][bb] + sigm(zi) * tanh_f(zg);
                c[uu][bb] = cc;
                const float hh = sigm(zo) * tanh_f(cc);
                hs[cur ^ 1][bb][u] = hh;
                h_out[(tt * BB + bg + bb) * (2 * HH) + off + u] = f2bf(hh);
            }
        }
        __syncthreads();
        cur ^= 1;
    }
}

// ---------- Emission: em = h1 @ W_sbj^T + b_sbj, (MTOT,37) f32 ----------
__global__ __launch_bounds__(256) void em_kernel(
    const unsigned short* __restrict__ h1, const float* __restrict__ Wsbj,
    const float* __restrict__ bsbj, float* __restrict__ em)
{
    const int o = blockIdx.x * 256 + threadIdx.x;
    if (o >= MTOT * KK) return;
    const int r = o / KK, k = o - r * KK;
    const unsigned short* hr = h1 + r * 512;
    const float* wrow = Wsbj + k * 512;
    float s = bsbj[k];
    for (int cidx = 0; cidx < 512; cidx += 4) {
        const ushort4 hv = *(const ushort4*)(hr + cidx);
        const float4  wv = *(const float4*)(wrow + cidx);
        s += bf2f(hv.x) * wv.x + bf2f(hv.y) * wv.y + bf2f(hv.z) * wv.z + bf2f(hv.w) * wv.w;
    }
    em[o] = s;
}

// ---------- CRF: one block (1 wave) per batch; numerator + forward logZ ----------
__global__ __launch_bounds__(64) void crf_kernel(
    const int* __restrict__ text, const int* __restrict__ sbj,
    const float* __restrict__ em,
    const float* __restrict__ start_t, const float* __restrict__ end_t,
    const float* __restrict__ trans, float* __restrict__ accum)
{
    const int b = blockIdx.x;
    const int tid = threadIdx.x;
    __shared__ float tr[KK * KK];
    __shared__ float sc[2][KK];
    for (int x = tid; x < KK * KK; x += 64) tr[x] = trans[x];

    int cnt = 0;
    for (int t = tid; t < TT; t += 64) cnt += (text[b * TT + t] != 0) ? 1 : 0;
    #pragma unroll
    for (int s = 32; s > 0; s >>= 1) cnt += __shfl_down(cnt, s, 64);
    const int len = __shfl(cnt, 0, 64);   // mask is prefix-contiguous

    __syncthreads();  // tr ready

    // numerator partial: sum_{1<=t<len} em[t,b,tag_t] + trans[tag_{t-1},tag_t]
    float part = 0.f;
    for (int t = tid; t < TT; t += 64) {
        if (t >= 1 && t < len) {
            const int tg = sbj[b * TT + t];
            const int tp = sbj[b * TT + t - 1];
            part += em[(t * BB + b) * KK + tg] + tr[tp * KK + tg];
        }
    }
    #pragma unroll
    for (int s = 32; s > 0; s >>= 1) part += __shfl_down(part, s, 64);

    // forward recursion
    if (tid < KK) sc[0][tid] = start_t[tid] + em[b * KK + tid];
    __syncthreads();
    int cur = 0;
    for (int t = 1; t < len; t++) {
        float nv = 0.f;
        if (tid < KK) {
            float mx = -1e30f;
            for (int k1 = 0; k1 < KK; k1++)
                mx = fmaxf(mx, sc[cur][k1] + tr[k1 * KK + tid]);
            float s = 0.f;
            for (int k1 = 0; k1 < KK; k1++)
                s += __expf(sc[cur][k1] + tr[k1 * KK + tid] - mx);
            nv = mx + __logf(s) + em[(t * BB + b) * KK + tid];
        }
        if (tid < KK) sc[cur ^ 1][tid] = nv;
        __syncthreads();
        cur ^= 1;
    }

    if (tid == 0) {
        const int tg0 = sbj[b * TT];
        const int tgl = sbj[b * TT + len - 1];
        const float num = start_t[tg0] + em[b * KK + tg0] + part + end_t[tgl];
        float mx = -1e30f;
        for (int k = 0; k < KK; k++) mx = fmaxf(mx, sc[cur][k] + end_t[k]);
        float s = 0.f;
        for (int k = 0; k < KK; k++) s += __expf(sc[cur][k] + end_t[k] - mx);
        const float logZ = mx + __logf(s);
        atomicAdd(&accum[0], num - logZ);
        atomicAdd(&accum[1], (float)len);
    }
}

__global__ void init_kernel(float* __restrict__ accum) {
    if (threadIdx.x < 2) accum[threadIdx.x] = 0.0f;
}
__global__ void final_kernel(const float* __restrict__ accum, float* __restrict__ out) {
    out[0] = -(accum[0] / accum[1]);
}

// ---------- launch ----------
extern "C" void kernel_launch(void* const* d_in, const int* in_sizes, int n_in,
                              void* d_out, int out_size, void* d_ws, size_t ws_size,
                              hipStream_t stream)
{
    (void)in_sizes; (void)n_in; (void)out_size; (void)ws_size;
    const int*   text  = (const int*)d_in[0];
    const int*   sbj   = (const int*)d_in[1];
    const float* emb   = (const float*)d_in[2];
    const float* Wih0f = (const float*)d_in[3];
    const float* Whh0f = (const float*)d_in[4];
    const float* b0f   = (const float*)d_in[5];
    const float* Wih0b = (const float*)d_in[6];
    const float* Whh0b = (const float*)d_in[7];
    const float* b0b   = (const float*)d_in[8];
    const float* Wih1f = (const float*)d_in[9];
    const float* Whh1f = (const float*)d_in[10];
    const float* b1f   = (const float*)d_in[11];
    const float* Wih1b = (const float*)d_in[12];
    const float* Whh1b = (const float*)d_in[13];
    const float* b1b   = (const float*)d_in[14];
    const float* Wsbj  = (const float*)d_in[15];
    const float* bsbj  = (const float*)d_in[16];
    const float* start_t = (const float*)d_in[17];
    const float* end_t   = (const float*)d_in[18];
    const float* trans   = (const float*)d_in[19];

    // workspace map (bytes); total ~98.4 MiB
    char* ws = (char*)d_ws;
    unsigned short* zf = (unsigned short*)(ws + 0);          // 16384*1024 bf16 = 32 MiB
    unsigned short* zb = (unsigned short*)(ws + 33554432);   // 32 MiB
    unsigned short* h0 = (unsigned short*)(ws + 67108864);   // 16384*512 bf16 = 16 MiB
    unsigned short* h1 = (unsigned short*)(ws + 83886080);   // 16 MiB
    float*          em = (float*)(ws + 100663296);           // 16384*37 f32
    float*         acc = (float*)(ws + 103088128);           // 2 f32
    float* out = (float*)d_out;

    init_kernel<<<1, 64, 0, stream>>>(acc);
    // layer 0 input projection (fused embedding gather), both directions
    gemm_embed<<<dim3(256, 16, 2), 256, 0, stream>>>(text, emb, Wih0f, b0f, Wih0b, b0b, zf, zb);
    // layer 0 recurrence (both directions) -> h0
    lstm_kernel<<<dim3(16, 2), 128, 0, stream>>>(zf, zb, Whh0f, Whh0b, h0);
    // layer 1 input projection (reuses zf/zb buffers)
    gemm_h<<<dim3(256, 16, 2), 256, 0, stream>>>(h0, Wih1f, b1f, Wih1b, b1b, zf, zb);
    // layer 1 recurrence -> h1
    lstm_kernel<<<dim3(16, 2), 128, 0, stream>>>(zf, zb, Whh1f, Whh1b, h1);
    // emissions
    em_kernel<<<(MTOT * KK) / 256, 256, 0, stream>>>(h1, Wsbj, bsbj, em);
    // CRF per batch + reduction
    crf_kernel<<<BB, 64, 0, stream>>>(text, sbj, em, start_t, end_t, trans, acc);
    final_kernel<<<1, 1, 0, stream>>>(acc, out);
}

// Round 2
// 19445.174 us; speedup vs baseline: 1.4130x; 1.4130x over previous
//
#include <hip/hip_runtime.h>
#include <math.h>

// Problem constants
#define TT 256      // sequence length
#define BB 64       // batch
#define DD 300      // embedding dim
#define HH 256      // hidden
#define KK 37       // CRF states
#define FH 1024     // 4*H
#define MTOT (TT*BB) // 16384 rows, time-major r = t*64 + b

// ---------- bf16 helpers (storage format for intermediates) ----------
__device__ __forceinline__ float bf2f(unsigned short u) {
    union { float f; unsigned int i; } v; v.i = ((unsigned int)u) << 16; return v.f;
}
__device__ __forceinline__ unsigned short f2bf(float f) {
    union { float f; unsigned int i; } v; v.f = f;
    unsigned int i = v.i;
    unsigned int r = (i + 0x7FFFu + ((i >> 16) & 1u)) >> 16; // RNE
    return (unsigned short)r;
}
__device__ __forceinline__ float sigm(float x)   { return 1.0f / (1.0f + __expf(-x)); }
__device__ __forceinline__ float tanh_f(float x) { return 2.0f / (1.0f + __expf(-2.0f * x)) - 1.0f; }

// ---------- GEMM 1: zin0 = gather(emb, text) @ Wih0^T + b0  (both dirs) ----------
// M=16384 (r=t*64+b), N=1024, K=300. Output bf16 (T,B,1024).
__global__ __launch_bounds__(256) void gemm_embed(
    const int* __restrict__ text, const float* __restrict__ emb,
    const float* __restrict__ Wf, const float* __restrict__ bf_,
    const float* __restrict__ Wb, const float* __restrict__ bb_,
    unsigned short* __restrict__ zf, unsigned short* __restrict__ zb)
{
    const int dir = blockIdx.z;
    const float* W    = dir ? Wb  : Wf;
    const float* bias = dir ? bb_ : bf_;
    unsigned short* out = dir ? zb : zf;

    __shared__ float As[16][65];
    __shared__ float Bs[16][65];

    const int bm = blockIdx.x * 64;
    const int bn = blockIdx.y * 64;
    const int tid = threadIdx.x;
    const int ml = tid >> 2;          // 0..63 (row within tile)
    const int kl = (tid & 3) * 4;     // 0,4,8,12

    const int r = bm + ml;
    const int t = r >> 6, b = r & 63;
    const int idx = text[b * TT + t];
    const float* arow = emb + idx * DD;
    const float* brow = W + (bn + ml) * DD;

    const int tx4 = (tid & 15) * 4, ty4 = (tid >> 4) * 4;
    float acc[4][4] = {};

    for (int kk = 0; kk < DD; kk += 16) {
        float4 av = make_float4(0.f, 0.f, 0.f, 0.f);
        float4 bv = make_float4(0.f, 0.f, 0.f, 0.f);
        const int d = kk + kl;
        if (d + 3 < DD) {            // DD % 4 == 0 -> no partial vectors
            av = *(const float4*)(arow + d);
            bv = *(const float4*)(brow + d);
        }
        As[kl + 0][ml] = av.x; As[kl + 1][ml] = av.y; As[kl + 2][ml] = av.z; As[kl + 3][ml] = av.w;
        Bs[kl + 0][ml] = bv.x; Bs[kl + 1][ml] = bv.y; Bs[kl + 2][ml] = bv.z; Bs[kl + 3][ml] = bv.w;
        __syncthreads();
        #pragma unroll
        for (int k = 0; k < 16; k++) {
            float a0 = As[k][ty4 + 0], a1 = As[k][ty4 + 1], a2 = As[k][ty4 + 2], a3 = As[k][ty4 + 3];
            float b0 = Bs[k][tx4 + 0], b1 = Bs[k][tx4 + 1], b2 = Bs[k][tx4 + 2], b3 = Bs[k][tx4 + 3];
            acc[0][0] += a0*b0; acc[0][1] += a0*b1; acc[0][2] += a0*b2; acc[0][3] += a0*b3;
            acc[1][0] += a1*b0; acc[1][1] += a1*b1; acc[1][2] += a1*b2; acc[1][3] += a1*b3;
            acc[2][0] += a2*b0; acc[2][1] += a2*b1; acc[2][2] += a2*b2; acc[2][3] += a2*b3;
            acc[3][0] += a3*b0; acc[3][1] += a3*b1; acc[3][2] += a3*b2; acc[3][3] += a3*b3;
        }
        __syncthreads();
    }
    #pragma unroll
    for (int i = 0; i < 4; i++) {
        const int rr = bm + ty4 + i;
        #pragma unroll
        for (int jj = 0; jj < 4; jj++) {
            const int nn = bn + tx4 + jj;
            out[rr * FH + nn] = f2bf(acc[i][jj] + bias[nn]);
        }
    }
}

// ---------- GEMM 2: zin1 = h0 @ Wih1^T + b1 (both dirs). A is bf16, K=512 ----------
__global__ __launch_bounds__(256) void gemm_h(
    const unsigned short* __restrict__ h0,
    const float* __restrict__ Wf, const float* __restrict__ bf_,
    const float* __restrict__ Wb, const float* __restrict__ bb_,
    unsigned short* __restrict__ zf, unsigned short* __restrict__ zb)
{
    const int dir = blockIdx.z;
    const float* W    = dir ? Wb  : Wf;
    const float* bias = dir ? bb_ : bf_;
    unsigned short* out = dir ? zb : zf;

    __shared__ float As[16][65];
    __shared__ float Bs[16][65];

    const int bm = blockIdx.x * 64;
    const int bn = blockIdx.y * 64;
    const int tid = threadIdx.x;
    const int ml = tid >> 2;
    const int kl = (tid & 3) * 4;

    const unsigned short* arow = h0 + (bm + ml) * 512;
    const float* brow = W + (bn + ml) * 512;

    const int tx4 = (tid & 15) * 4, ty4 = (tid >> 4) * 4;
    float acc[4][4] = {};

    for (int kk = 0; kk < 512; kk += 16) {
        const int d = kk + kl;
        ushort4 av4 = *(const ushort4*)(arow + d);
        float4  bv  = *(const float4*)(brow + d);
        As[kl + 0][ml] = bf2f(av4.x); As[kl + 1][ml] = bf2f(av4.y);
        As[kl + 2][ml] = bf2f(av4.z); As[kl + 3][ml] = bf2f(av4.w);
        Bs[kl + 0][ml] = bv.x; Bs[kl + 1][ml] = bv.y; Bs[kl + 2][ml] = bv.z; Bs[kl + 3][ml] = bv.w;
        __syncthreads();
        #pragma unroll
        for (int k = 0; k < 16; k++) {
            float a0 = As[k][ty4 + 0], a1 = As[k][ty4 + 1], a2 = As[k][ty4 + 2], a3 = As[k][ty4 + 3];
            float b0 = Bs[k][tx4 + 0], b1 = Bs[k][tx4 + 1], b2 = Bs[k][tx4 + 2], b3 = Bs[k][tx4 + 3];
            acc[0][0] += a0*b0; acc[0][1] += a0*b1; acc[0][2] += a0*b2; acc[0][3] += a0*b3;
            acc[1][0] += a1*b0; acc[1][1] += a1*b1; acc[1][2] += a1*b2; acc[1][3] += a1*b3;
            acc[2][0] += a2*b0; acc[2][1] += a2*b1; acc[2][2] += a2*b2; acc[2][3] += a2*b3;
            acc[3][0] += a3*b0; acc[3][1] += a3*b1; acc[3][2] += a3*b2; acc[3][3] += a3*b3;
        }
        __syncthreads();
    }
    #pragma unroll
    for (int i = 0; i < 4; i++) {
        const int rr = bm + ty4 + i;
        #pragma unroll
        for (int jj = 0; jj < 4; jj++) {
            const int nn = bn + tx4 + jj;
            out[rr * FH + nn] = f2bf(acc[i][jj] + bias[nn]);
        }
    }
}

// ---------- LSTM recurrence: grid (16 batch-groups, 2 dirs), 256 threads ----------
// Thread u owns hidden unit u: Whh rows {u, 256+u, 512+u, 768+u}, for 4 batches.
// 4 waves/block -> all 4 SIMDs of a CU active. h double-buffered in LDS (f32);
// LDS h reads are wave-broadcast (all lanes read the same address -> conflict-free).
// Per-CU per-step model: 4096 FMA/thread -> 8192 VALU cy; Whh 1 MB from L2 -> ~8K cy.
__global__ __launch_bounds__(256) void lstm_kernel(
    const unsigned short* __restrict__ zin_f, const unsigned short* __restrict__ zin_b,
    const float* __restrict__ Whh_f, const float* __restrict__ Whh_b,
    unsigned short* __restrict__ h_out)  // (T,B,512) bf16; fwd->cols[0:256), bwd->[256:512)
{
    const int dir = blockIdx.y;
    const unsigned short* zin = dir ? zin_b : zin_f;
    const float* Whh = dir ? Whh_b : Whh_f;
    const int off = dir ? HH : 0;

    const int bg = blockIdx.x * 4;
    const int u = threadIdx.x;          // hidden unit 0..255

    __shared__ float hs[2][4][HH];      // [buf][batch][unit], 8 KB
    for (int x = u; x < 2 * 4 * HH; x += 256) ((float*)hs)[x] = 0.0f;
    __syncthreads();

    float c[4] = {};                    // cell state per batch
    int cur = 0;

    const float* wr[4];
    #pragma unroll
    for (int g = 0; g < 4; g++) wr[g] = Whh + (g * HH + u) * HH;

    for (int ts = 0; ts < TT; ts++) {
        const int tt = dir ? (TT - 1 - ts) : ts;

        // prefetch zin for this step (coalesced across lanes in u)
        float z[4][4];                  // [gate][batch]
        #pragma unroll
        for (int bb = 0; bb < 4; bb++) {
            const int base = (tt * BB + bg + bb) * FH;
            #pragma unroll
            for (int g = 0; g < 4; g++)
                z[g][bb] = bf2f(zin[base + g * HH + u]);
        }

        float acc[4][4] = {};           // [gate][batch]
        #pragma unroll 4
        for (int k4 = 0; k4 < HH / 4; k4++) {
            float4 h4[4];
            #pragma unroll
            for (int bb = 0; bb < 4; bb++)
                h4[bb] = *(const float4*)&hs[cur][bb][k4 * 4];   // broadcast
            #pragma unroll
            for (int g = 0; g < 4; g++) {
                const float4 w = *(const float4*)(wr[g] + k4 * 4);
                #pragma unroll
                for (int bb = 0; bb < 4; bb++)
                    acc[g][bb] += w.x * h4[bb].x + w.y * h4[bb].y + w.z * h4[bb].z + w.w * h4[bb].w;
            }
        }

        #pragma unroll
        for (int bb = 0; bb < 4; bb++) {
            const float zi  = acc[0][bb] + z[0][bb];
            const float zf_ = acc[1][bb] + z[1][bb];
            const float zg  = acc[2][bb] + z[2][bb];
            const float zo  = acc[3][bb] + z[3][bb];
            const float cc = sigm(zf_) * c[bb] + sigm(zi) * tanh_f(zg);
            c[bb] = cc;
            const float hh = sigm(zo) * tanh_f(cc);
            hs[cur ^ 1][bb][u] = hh;
            h_out[(tt * BB + bg + bb) * (2 * HH) + off + u] = f2bf(hh);
        }
        __syncthreads();
        cur ^= 1;
    }
}

// ---------- Emission: em = h1 @ W_sbj^T + b_sbj, (MTOT,37) f32 ----------
__global__ __launch_bounds__(256) void em_kernel(
    const unsigned short* __restrict__ h1, const float* __restrict__ Wsbj,
    const float* __restrict__ bsbj, float* __restrict__ em)
{
    const int o = blockIdx.x * 256 + threadIdx.x;
    if (o >= MTOT * KK) return;
    const int r = o / KK, k = o - r * KK;
    const unsigned short* hr = h1 + r * 512;
    const float* wrow = Wsbj + k * 512;
    float s = bsbj[k];
    for (int cidx = 0; cidx < 512; cidx += 4) {
        const ushort4 hv = *(const ushort4*)(hr + cidx);
        const float4  wv = *(const float4*)(wrow + cidx);
        s += bf2f(hv.x) * wv.x + bf2f(hv.y) * wv.y + bf2f(hv.z) * wv.z + bf2f(hv.w) * wv.w;
    }
    em[o] = s;
}

// ---------- CRF: one block (1 wave) per batch; numerator + forward logZ ----------
__global__ __launch_bounds__(64) void crf_kernel(
    const int* __restrict__ text, const int* __restrict__ sbj,
    const float* __restrict__ em,
    const float* __restrict__ start_t, const float* __restrict__ end_t,
    const float* __restrict__ trans, float* __restrict__ accum)
{
    const int b = blockIdx.x;
    const int tid = threadIdx.x;
    __shared__ float tr[KK * KK];
    __shared__ float sc[2][KK];
    for (int x = tid; x < KK * KK; x += 64) tr[x] = trans[x];

    int cnt = 0;
    for (int t = tid; t < TT; t += 64) cnt += (text[b * TT + t] != 0) ? 1 : 0;
    #pragma unroll
    for (int s = 32; s > 0; s >>= 1) cnt += __shfl_down(cnt, s, 64);
    const int len = __shfl(cnt, 0, 64);   // mask is prefix-contiguous

    __syncthreads();  // tr ready

    // numerator partial: sum_{1<=t<len} em[t,b,tag_t] + trans[tag_{t-1},tag_t]
    float part = 0.f;
    for (int t = tid; t < TT; t += 64) {
        if (t >= 1 && t < len) {
            const int tg = sbj[b * TT + t];
            const int tp = sbj[b * TT + t - 1];
            part += em[(t * BB + b) * KK + tg] + tr[tp * KK + tg];
        }
    }
    #pragma unroll
    for (int s = 32; s > 0; s >>= 1) part += __shfl_down(part, s, 64);

    // forward recursion
    if (tid < KK) sc[0][tid] = start_t[tid] + em[b * KK + tid];
    __syncthreads();
    int cur = 0;
    for (int t = 1; t < len; t++) {
        float nv = 0.f;
        if (tid < KK) {
            float mx = -1e30f;
            for (int k1 = 0; k1 < KK; k1++)
                mx = fmaxf(mx, sc[cur][k1] + tr[k1 * KK + tid]);
            float s = 0.f;
            for (int k1 = 0; k1 < KK; k1++)
                s += __expf(sc[cur][k1] + tr[k1 * KK + tid] - mx);
            nv = mx + __logf(s) + em[(t * BB + b) * KK + tid];
        }
        if (tid < KK) sc[cur ^ 1][tid] = nv;
        __syncthreads();
        cur ^= 1;
    }

    if (tid == 0) {
        const int tg0 = sbj[b * TT];
        const int tgl = sbj[b * TT + len - 1];
        const float num = start_t[tg0] + em[b * KK + tg0] + part + end_t[tgl];
        float mx = -1e30f;
        for (int k = 0; k < KK; k++) mx = fmaxf(mx, sc[cur][k] + end_t[k]);
        float s = 0.f;
        for (int k = 0; k < KK; k++) s += __expf(sc[cur][k] + end_t[k] - mx);
        const float logZ = mx + __logf(s);
        atomicAdd(&accum[0], num - logZ);
        atomicAdd(&accum[1], (float)len);
    }
}

__global__ void init_kernel(float* __restrict__ accum) {
    if (threadIdx.x < 2) accum[threadIdx.x] = 0.0f;
}
__global__ void final_kernel(const float* __restrict__ accum, float* __restrict__ out) {
    out[0] = -(accum[0] / accum[1]);
}

// ---------- launch ----------
extern "C" void kernel_launch(void* const* d_in, const int* in_sizes, int n_in,
                              void* d_out, int out_size, void* d_ws, size_t ws_size,
                              hipStream_t stream)
{
    (void)in_sizes; (void)n_in; (void)out_size; (void)ws_size;
    const int*   text  = (const int*)d_in[0];
    const int*   sbj   = (const int*)d_in[1];
    const float* emb   = (const float*)d_in[2];
    const float* Wih0f = (const float*)d_in[3];
    const float* Whh0f = (const float*)d_in[4];
    const float* b0f   = (const float*)d_in[5];
    const float* Wih0b = (const float*)d_in[6];
    const float* Whh0b = (const float*)d_in[7];
    const float* b0b   = (const float*)d_in[8];
    const float* Wih1f = (const float*)d_in[9];
    const float* Whh1f = (const float*)d_in[10];
    const float* b1f   = (const float*)d_in[11];
    const float* Wih1b = (const float*)d_in[12];
    const float* Whh1b = (const float*)d_in[13];
    const float* b1b   = (const float*)d_in[14];
    const float* Wsbj  = (const float*)d_in[15];
    const float* bsbj  = (const float*)d_in[16];
    const float* start_t = (const float*)d_in[17];
    const float* end_t   = (const float*)d_in[18];
    const float* trans   = (const float*)d_in[19];

    // workspace map (bytes); total ~98.4 MiB
    char* ws = (char*)d_ws;
    unsigned short* zf = (unsigned short*)(ws + 0);          // 16384*1024 bf16 = 32 MiB
    unsigned short* zb = (unsigned short*)(ws + 33554432);   // 32 MiB
    unsigned short* h0 = (unsigned short*)(ws + 67108864);   // 16384*512 bf16 = 16 MiB
    unsigned short* h1 = (unsigned short*)(ws + 83886080);   // 16 MiB
    float*          em = (float*)(ws + 100663296);           // 16384*37 f32
    float*         acc = (float*)(ws + 103088128);           // 2 f32
    float* out = (float*)d_out;

    init_kernel<<<1, 64, 0, stream>>>(acc);
    // layer 0 input projection (fused embedding gather), both directions
    gemm_embed<<<dim3(256, 16, 2), 256, 0, stream>>>(text, emb, Wih0f, b0f, Wih0b, b0b, zf, zb);
    // layer 0 recurrence (both directions) -> h0
    lstm_kernel<<<dim3(16, 2), 256, 0, stream>>>(zf, zb, Whh0f, Whh0b, h0);
    // layer 1 input projection (reuses zf/zb buffers)
    gemm_h<<<dim3(256, 16, 2), 256, 0, stream>>>(h0, Wih1f, b1f, Wih1b, b1b, zf, zb);
    // layer 1 recurrence -> h1
    lstm_kernel<<<dim3(16, 2), 256, 0, stream>>>(zf, zb, Whh1f, Whh1b, h1);
    // emissions
    em_kernel<<<(MTOT * KK) / 256, 256, 0, stream>>>(h1, Wsbj, bsbj, em);
    // CRF per batch + reduction
    crf_kernel<<<BB, 64, 0, stream>>>(text, sbj, em, start_t, end_t, trans, acc);
    final_kernel<<<1, 1, 0, stream>>>(acc, out);
}

// Round 3
// 5570.107 us; speedup vs baseline: 4.9329x; 3.4910x over previous
//
#include <hip/hip_runtime.h>
#include <math.h>

// Problem constants
#define TT 256      // sequence length
#define BB 64       // batch
#define DD 300      // embedding dim
#define HH 256      // hidden
#define KK 37       // CRF states
#define FH 1024     // 4*H
#define MTOT (TT*BB) // 16384 rows, time-major r = t*64 + b

// ---------- bf16 helpers ----------
__device__ __forceinline__ float bf2f(unsigned short u) {
    union { float f; unsigned int i; } v; v.i = ((unsigned int)u) << 16; return v.f;
}
__device__ __forceinline__ unsigned short f2bf(float f) {
    union { float f; unsigned int i; } v; v.f = f;
    unsigned int i = v.i;
    unsigned int r = (i + 0x7FFFu + ((i >> 16) & 1u)) >> 16; // RNE
    return (unsigned short)r;
}
// unpack 2 bf16 from a uint32 (lo = first element, hi = second)
__device__ __forceinline__ float bflo(unsigned int w) {
    union { float f; unsigned int i; } v; v.i = w << 16; return v.f;
}
__device__ __forceinline__ float bfhi(unsigned int w) {
    union { float f; unsigned int i; } v; v.i = w & 0xFFFF0000u; return v.f;
}
__device__ __forceinline__ float sigm(float x)   { return 1.0f / (1.0f + __expf(-x)); }
__device__ __forceinline__ float tanh_f(float x) { return 2.0f / (1.0f + __expf(-2.0f * x)) - 1.0f; }

// permute gate-major col (g*256+unit) -> interleaved (unit*4+g)
__device__ __forceinline__ int perm_col(int nn) { return ((nn & 255) << 2) | (nn >> 8); }

// ---------- prep: WhhT bf16 [k][unit*4+gate], all 4 matrices ----------
__global__ __launch_bounds__(256) void conv_whh(
    const float* __restrict__ w0f, const float* __restrict__ w0b,
    const float* __restrict__ w1f, const float* __restrict__ w1b,
    unsigned short* __restrict__ WT)   // 4 x [256][1024]
{
    const int which = blockIdx.y;
    const float* W = which == 0 ? w0f : which == 1 ? w0b : which == 2 ? w1f : w1b;
    const int idx = blockIdx.x * 256 + threadIdx.x;   // 0..262143
    const int k = idx >> 10, p = idx & 1023;
    const int u = p >> 2, g = p & 3;
    WT[which * (HH * FH) + idx] = f2bf(W[(g * HH + u) * HH + k]);
}

// ---------- prep: WsbjT f32 [512][37] ----------
__global__ __launch_bounds__(256) void conv_wsbj(
    const float* __restrict__ Wsbj, float* __restrict__ WT)
{
    const int idx = blockIdx.x * 256 + threadIdx.x;
    if (idx >= 512 * KK) return;
    const int c = idx / KK, k = idx - c * KK;
    WT[idx] = Wsbj[k * 512 + c];
}

// ---------- GEMM 1: zin0 = gather(emb, text) @ Wih0^T + b0 (both dirs) ----------
// Output bf16 (T,B,1024) with gate-interleaved cols.
__global__ __launch_bounds__(256) void gemm_embed(
    const int* __restrict__ text, const float* __restrict__ emb,
    const float* __restrict__ Wf, const float* __restrict__ bf_,
    const float* __restrict__ Wb, const float* __restrict__ bb_,
    unsigned short* __restrict__ zf, unsigned short* __restrict__ zb)
{
    const int dir = blockIdx.z;
    const float* W    = dir ? Wb  : Wf;
    const float* bias = dir ? bb_ : bf_;
    unsigned short* out = dir ? zb : zf;

    __shared__ float As[16][65];
    __shared__ float Bs[16][65];

    const int bm = blockIdx.x * 64;
    const int bn = blockIdx.y * 64;
    const int tid = threadIdx.x;
    const int ml = tid >> 2;
    const int kl = (tid & 3) * 4;

    const int r = bm + ml;
    const int t = r >> 6, b = r & 63;
    const int idx = text[b * TT + t];
    const float* arow = emb + idx * DD;
    const float* brow = W + (bn + ml) * DD;

    const int tx4 = (tid & 15) * 4, ty4 = (tid >> 4) * 4;
    float acc[4][4] = {};

    for (int kk = 0; kk < DD; kk += 16) {
        float4 av = make_float4(0.f, 0.f, 0.f, 0.f);
        float4 bv = make_float4(0.f, 0.f, 0.f, 0.f);
        const int d = kk + kl;
        if (d + 3 < DD) {
            av = *(const float4*)(arow + d);
            bv = *(const float4*)(brow + d);
        }
        As[kl + 0][ml] = av.x; As[kl + 1][ml] = av.y; As[kl + 2][ml] = av.z; As[kl + 3][ml] = av.w;
        Bs[kl + 0][ml] = bv.x; Bs[kl + 1][ml] = bv.y; Bs[kl + 2][ml] = bv.z; Bs[kl + 3][ml] = bv.w;
        __syncthreads();
        #pragma unroll
        for (int k = 0; k < 16; k++) {
            float a0 = As[k][ty4 + 0], a1 = As[k][ty4 + 1], a2 = As[k][ty4 + 2], a3 = As[k][ty4 + 3];
            float b0 = Bs[k][tx4 + 0], b1 = Bs[k][tx4 + 1], b2 = Bs[k][tx4 + 2], b3 = Bs[k][tx4 + 3];
            acc[0][0] += a0*b0; acc[0][1] += a0*b1; acc[0][2] += a0*b2; acc[0][3] += a0*b3;
            acc[1][0] += a1*b0; acc[1][1] += a1*b1; acc[1][2] += a1*b2; acc[1][3] += a1*b3;
            acc[2][0] += a2*b0; acc[2][1] += a2*b1; acc[2][2] += a2*b2; acc[2][3] += a2*b3;
            acc[3][0] += a3*b0; acc[3][1] += a3*b1; acc[3][2] += a3*b2; acc[3][3] += a3*b3;
        }
        __syncthreads();
    }
    #pragma unroll
    for (int i = 0; i < 4; i++) {
        const int rr = bm + ty4 + i;
        #pragma unroll
        for (int jj = 0; jj < 4; jj++) {
            const int nn = bn + tx4 + jj;
            out[rr * FH + perm_col(nn)] = f2bf(acc[i][jj] + bias[nn]);
        }
    }
}

// ---------- GEMM 2: zin1 = h0 @ Wih1^T + b1 (both dirs). A bf16, K=512 ----------
__global__ __launch_bounds__(256) void gemm_h(
    const unsigned short* __restrict__ h0,
    const float* __restrict__ Wf, const float* __restrict__ bf_,
    const float* __restrict__ Wb, const float* __restrict__ bb_,
    unsigned short* __restrict__ zf, unsigned short* __restrict__ zb)
{
    const int dir = blockIdx.z;
    const float* W    = dir ? Wb  : Wf;
    const float* bias = dir ? bb_ : bf_;
    unsigned short* out = dir ? zb : zf;

    __shared__ float As[16][65];
    __shared__ float Bs[16][65];

    const int bm = blockIdx.x * 64;
    const int bn = blockIdx.y * 64;
    const int tid = threadIdx.x;
    const int ml = tid >> 2;
    const int kl = (tid & 3) * 4;

    const unsigned short* arow = h0 + (bm + ml) * 512;
    const float* brow = W + (bn + ml) * 512;

    const int tx4 = (tid & 15) * 4, ty4 = (tid >> 4) * 4;
    float acc[4][4] = {};

    for (int kk = 0; kk < 512; kk += 16) {
        const int d = kk + kl;
        ushort4 av4 = *(const ushort4*)(arow + d);
        float4  bv  = *(const float4*)(brow + d);
        As[kl + 0][ml] = bf2f(av4.x); As[kl + 1][ml] = bf2f(av4.y);
        As[kl + 2][ml] = bf2f(av4.z); As[kl + 3][ml] = bf2f(av4.w);
        Bs[kl + 0][ml] = bv.x; Bs[kl + 1][ml] = bv.y; Bs[kl + 2][ml] = bv.z; Bs[kl + 3][ml] = bv.w;
        __syncthreads();
        #pragma unroll
        for (int k = 0; k < 16; k++) {
            float a0 = As[k][ty4 + 0], a1 = As[k][ty4 + 1], a2 = As[k][ty4 + 2], a3 = As[k][ty4 + 3];
            float b0 = Bs[k][tx4 + 0], b1 = Bs[k][tx4 + 1], b2 = Bs[k][tx4 + 2], b3 = Bs[k][tx4 + 3];
            acc[0][0] += a0*b0; acc[0][1] += a0*b1; acc[0][2] += a0*b2; acc[0][3] += a0*b3;
            acc[1][0] += a1*b0; acc[1][1] += a1*b1; acc[1][2] += a1*b2; acc[1][3] += a1*b3;
            acc[2][0] += a2*b0; acc[2][1] += a2*b1; acc[2][2] += a2*b2; acc[2][3] += a2*b3;
            acc[3][0] += a3*b0; acc[3][1] += a3*b1; acc[3][2] += a3*b2; acc[3][3] += a3*b3;
        }
        __syncthreads();
    }
    #pragma unroll
    for (int i = 0; i < 4; i++) {
        const int rr = bm + ty4 + i;
        #pragma unroll
        for (int jj = 0; jj < 4; jj++) {
            const int nn = bn + tx4 + jj;
            out[rr * FH + perm_col(nn)] = f2bf(acc[i][jj] + bias[nn]);
        }
    }
}

// ---------- LSTM recurrence: grid (64 batches, 2 dirs), 256 threads ----------
// Thread u owns unit u (all 4 gates, interleaved cols 4u..4u+3), 1 batch/block.
// WhhT bf16 [k][1024] -> per-k the block reads 2 KB fully coalesced (8 B/lane).
// Per-CU step budget: VALU ~4.2K cy, VMEM 512 KB@135 B/cy ~3.9K cy, DS ~3K cy.
__global__ __launch_bounds__(256) void lstm_kernel(
    const unsigned short* __restrict__ zin_f, const unsigned short* __restrict__ zin_b,
    const unsigned short* __restrict__ WTf, const unsigned short* __restrict__ WTb,
    unsigned short* __restrict__ h_out)  // (T,B,512) bf16; fwd cols [0:256), bwd [256:512)
{
    const int dir = blockIdx.y;
    const unsigned short* zin = dir ? zin_b : zin_f;
    const unsigned short* WT  = dir ? WTb : WTf;
    const int off = dir ? HH : 0;

    const int b = blockIdx.x;           // batch
    const int u = threadIdx.x;          // unit 0..255

    __shared__ float hs[2][HH];
    hs[0][u] = 0.0f;
    float c = 0.0f;
    int cur = 0;
    __syncthreads();

    const unsigned short* wbase = WT + 4 * u;

    for (int ts = 0; ts < TT; ts++) {
        const int tt = dir ? (TT - 1 - ts) : ts;
        const int row = tt * BB + b;

        // zin for this step: 4 gates of unit u, coalesced ushort4
        const ushort4 zv = *(const ushort4*)(zin + row * FH + 4 * u);

        float a0 = 0.f, a1 = 0.f, a2 = 0.f, a3 = 0.f;
        #pragma unroll 4
        for (int k4 = 0; k4 < HH / 4; k4++) {
            const float4 hv = *(const float4*)&hs[cur][k4 * 4];   // LDS broadcast
            const uint2 w0 = *(const uint2*)(wbase + (k4 * 4 + 0) * FH);
            const uint2 w1 = *(const uint2*)(wbase + (k4 * 4 + 1) * FH);
            const uint2 w2 = *(const uint2*)(wbase + (k4 * 4 + 2) * FH);
            const uint2 w3 = *(const uint2*)(wbase + (k4 * 4 + 3) * FH);
            a0 += bflo(w0.x) * hv.x; a1 += bfhi(w0.x) * hv.x; a2 += bflo(w0.y) * hv.x; a3 += bfhi(w0.y) * hv.x;
            a0 += bflo(w1.x) * hv.y; a1 += bfhi(w1.x) * hv.y; a2 += bflo(w1.y) * hv.y; a3 += bfhi(w1.y) * hv.y;
            a0 += bflo(w2.x) * hv.z; a1 += bfhi(w2.x) * hv.z; a2 += bflo(w2.y) * hv.z; a3 += bfhi(w2.y) * hv.z;
            a0 += bflo(w3.x) * hv.w; a1 += bfhi(w3.x) * hv.w; a2 += bflo(w3.y) * hv.w; a3 += bfhi(w3.y) * hv.w;
        }

        const float zi  = a0 + bf2f(zv.x);
        const float zf_ = a1 + bf2f(zv.y);
        const float zg  = a2 + bf2f(zv.z);
        const float zo  = a3 + bf2f(zv.w);
        const float cc = sigm(zf_) * c + sigm(zi) * tanh_f(zg);
        c = cc;
        const float hh = sigm(zo) * tanh_f(cc);
        hs[cur ^ 1][u] = hh;
        h_out[row * (2 * HH) + off + u] = f2bf(hh);
        __syncthreads();
        cur ^= 1;
    }
}

// ---------- Emission: em = h1 @ WsbjT + b_sbj, (MTOT,37) f32 ----------
// WsbjT [c][37]: lanes (consecutive k) read contiguous f32; h1 broadcast per row.
__global__ __launch_bounds__(256) void em_kernel(
    const unsigned short* __restrict__ h1, const float* __restrict__ WsbjT,
    const float* __restrict__ bsbj, float* __restrict__ em)
{
    const int o = blockIdx.x * 256 + threadIdx.x;
    if (o >= MTOT * KK) return;
    const int r = o / KK, k = o - r * KK;
    const unsigned short* hr = h1 + r * 512;
    float s = bsbj[k];
    #pragma unroll 4
    for (int cidx = 0; cidx < 512; cidx++) {
        s += bf2f(hr[cidx]) * WsbjT[cidx * KK + k];
    }
    em[o] = s;
}

// ---------- CRF: one block (1 wave) per batch ----------
__global__ __launch_bounds__(64) void crf_kernel(
    const int* __restrict__ text, const int* __restrict__ sbj,
    const float* __restrict__ em,
    const float* __restrict__ start_t, const float* __restrict__ end_t,
    const float* __restrict__ trans, float* __restrict__ accum)
{
    const int b = blockIdx.x;
    const int tid = threadIdx.x;
    __shared__ float tr[KK * KK];
    __shared__ float sc[2][KK];
    for (int x = tid; x < KK * KK; x += 64) tr[x] = trans[x];

    int cnt = 0;
    for (int t = tid; t < TT; t += 64) cnt += (text[b * TT + t] != 0) ? 1 : 0;
    #pragma unroll
    for (int s = 32; s > 0; s >>= 1) cnt += __shfl_down(cnt, s, 64);
    const int len = __shfl(cnt, 0, 64);

    __syncthreads();

    float part = 0.f;
    for (int t = tid; t < TT; t += 64) {
        if (t >= 1 && t < len) {
            const int tg = sbj[b * TT + t];
            const int tp = sbj[b * TT + t - 1];
            part += em[(t * BB + b) * KK + tg] + tr[tp * KK + tg];
        }
    }
    #pragma unroll
    for (int s = 32; s > 0; s >>= 1) part += __shfl_down(part, s, 64);

    if (tid < KK) sc[0][tid] = start_t[tid] + em[b * KK + tid];
    __syncthreads();
    int cur = 0;
    for (int t = 1; t < len; t++) {
        float nv = 0.f;
        if (tid < KK) {
            float mx = -1e30f;
            for (int k1 = 0; k1 < KK; k1++)
                mx = fmaxf(mx, sc[cur][k1] + tr[k1 * KK + tid]);
            float s = 0.f;
            for (int k1 = 0; k1 < KK; k1++)
                s += __expf(sc[cur][k1] + tr[k1 * KK + tid] - mx);
            nv = mx + __logf(s) + em[(t * BB + b) * KK + tid];
        }
        if (tid < KK) sc[cur ^ 1][tid] = nv;
        __syncthreads();
        cur ^= 1;
    }

    if (tid == 0) {
        const int tg0 = sbj[b * TT];
        const int tgl = sbj[b * TT + len - 1];
        const float num = start_t[tg0] + em[b * KK + tg0] + part + end_t[tgl];
        float mx = -1e30f;
        for (int k = 0; k < KK; k++) mx = fmaxf(mx, sc[cur][k] + end_t[k]);
        float s = 0.f;
        for (int k = 0; k < KK; k++) s += __expf(sc[cur][k] + end_t[k] - mx);
        const float logZ = mx + __logf(s);
        atomicAdd(&accum[0], num - logZ);
        atomicAdd(&accum[1], (float)len);
    }
}

__global__ void init_kernel(float* __restrict__ accum) {
    if (threadIdx.x < 2) accum[threadIdx.x] = 0.0f;
}
__global__ void final_kernel(const float* __restrict__ accum, float* __restrict__ out) {
    out[0] = -(accum[0] / accum[1]);
}

// ---------- launch ----------
extern "C" void kernel_launch(void* const* d_in, const int* in_sizes, int n_in,
                              void* d_out, int out_size, void* d_ws, size_t ws_size,
                              hipStream_t stream)
{
    (void)in_sizes; (void)n_in; (void)out_size; (void)ws_size;
    const int*   text  = (const int*)d_in[0];
    const int*   sbj   = (const int*)d_in[1];
    const float* emb   = (const float*)d_in[2];
    const float* Wih0f = (const float*)d_in[3];
    const float* Whh0f = (const float*)d_in[4];
    const float* b0f   = (const float*)d_in[5];
    const float* Wih0b = (const float*)d_in[6];
    const float* Whh0b = (const float*)d_in[7];
    const float* b0b   = (const float*)d_in[8];
    const float* Wih1f = (const float*)d_in[9];
    const float* Whh1f = (const float*)d_in[10];
    const float* b1f   = (const float*)d_in[11];
    const float* Wih1b = (const float*)d_in[12];
    const float* Whh1b = (const float*)d_in[13];
    const float* b1b   = (const float*)d_in[14];
    const float* Wsbj  = (const float*)d_in[15];
    const float* bsbj  = (const float*)d_in[16];
    const float* start_t = (const float*)d_in[17];
    const float* end_t   = (const float*)d_in[18];
    const float* trans   = (const float*)d_in[19];

    // workspace map (bytes), max ~102.8 MiB (em overlaps dead zf region)
    char* ws = (char*)d_ws;
    unsigned short* zf   = (unsigned short*)(ws + 0);           // 32 MiB
    unsigned short* zb   = (unsigned short*)(ws + 33554432);    // 32 MiB
    unsigned short* h0   = (unsigned short*)(ws + 67108864);    // 16 MiB
    unsigned short* h1   = (unsigned short*)(ws + 83886080);    // 16 MiB
    unsigned short* WhhT = (unsigned short*)(ws + 100663296);   // 4 x 512 KiB
    float*        WsbjT  = (float*)(ws + 102760448);            // 76 KiB
    float*          acc  = (float*)(ws + 102836224);            // 8 B
    float*           em  = (float*)(ws + 0);                    // 2.4 MiB, reuses zf (dead after lstm1)
    float* out = (float*)d_out;

    unsigned short* WT0f = WhhT + 0 * (HH * FH);
    unsigned short* WT0b = WhhT + 1 * (HH * FH);
    unsigned short* WT1f = WhhT + 2 * (HH * FH);
    unsigned short* WT1b = WhhT + 3 * (HH * FH);

    init_kernel<<<1, 64, 0, stream>>>(acc);
    conv_whh<<<dim3(1024, 4), 256, 0, stream>>>(Whh0f, Whh0b, Whh1f, Whh1b, WhhT);
    conv_wsbj<<<dim3(74), 256, 0, stream>>>(Wsbj, WsbjT);

    gemm_embed<<<dim3(256, 16, 2), 256, 0, stream>>>(text, emb, Wih0f, b0f, Wih0b, b0b, zf, zb);
    lstm_kernel<<<dim3(BB, 2), 256, 0, stream>>>(zf, zb, WT0f, WT0b, h0);
    gemm_h<<<dim3(256, 16, 2), 256, 0, stream>>>(h0, Wih1f, b1f, Wih1b, b1b, zf, zb);
    lstm_kernel<<<dim3(BB, 2), 256, 0, stream>>>(zf, zb, WT1f, WT1b, h1);
    em_kernel<<<(MTOT * KK + 255) / 256, 256, 0, stream>>>(h1, WsbjT, bsbj, em);
    crf_kernel<<<BB, 64, 0, stream>>>(text, sbj, em, start_t, end_t, trans, acc);
    final_kernel<<<1, 1, 0, stream>>>(acc, out);
}

// Round 4
// 3928.091 us; speedup vs baseline: 6.9949x; 1.4180x over previous
//
#include <hip/hip_runtime.h>
#include <math.h>

// Problem constants
#define TT 256      // sequence length
#define BB 64       // batch
#define DD 300      // embedding dim
#define HH 256      // hidden
#define KK 37       // CRF states
#define FH 1024     // 4*H
#define MTOT (TT*BB) // 16384 rows, time-major r = t*64 + b

// ---------- bf16 helpers ----------
__device__ __forceinline__ float bf2f(unsigned short u) {
    union { float f; unsigned int i; } v; v.i = ((unsigned int)u) << 16; return v.f;
}
__device__ __forceinline__ unsigned short f2bf(float f) {
    union { float f; unsigned int i; } v; v.f = f;
    unsigned int i = v.i;
    unsigned int r = (i + 0x7FFFu + ((i >> 16) & 1u)) >> 16; // RNE
    return (unsigned short)r;
}
__device__ __forceinline__ float bflo(unsigned int w) {
    union { float f; unsigned int i; } v; v.i = w << 16; return v.f;
}
__device__ __forceinline__ float bfhi(unsigned int w) {
    union { float f; unsigned int i; } v; v.i = w & 0xFFFF0000u; return v.f;
}
__device__ __forceinline__ float sigm(float x)   { return 1.0f / (1.0f + __expf(-x)); }
__device__ __forceinline__ float tanh_f(float x) { return 2.0f / (1.0f + __expf(-2.0f * x)) - 1.0f; }

// permute gate-major col (g*256+unit) -> interleaved (unit*4+g)
__device__ __forceinline__ int perm_col(int nn) { return ((nn & 255) << 2) | (nn >> 8); }

// ---------- prep: WP packed bf16 weights for the lstm kernel ----------
// Word layout per matrix m (131072 uint32):
//   word[((kq*32 + j2)*256 + u)*4 + w4],  k = kq*64 + j2*2 + (w4>>1)
//   w4&1==0 -> pack(gate_i, gate_f) at k ; w4&1==1 -> pack(gate_g, gate_o) at k
__global__ __launch_bounds__(256) void conv_whh(
    const float* __restrict__ w0f, const float* __restrict__ w0b,
    const float* __restrict__ w1f, const float* __restrict__ w1b,
    unsigned int* __restrict__ WP)
{
    const int idx = blockIdx.x * 256 + threadIdx.x;      // 0 .. 4*131072-1
    const int m = idx >> 17;
    const int r = idx & 131071;
    const float* W = m == 0 ? w0f : m == 1 ? w0b : m == 2 ? w1f : w1b;
    const int w4 = r & 3;
    const int u  = (r >> 2) & 255;
    const int j2 = (r >> 10) & 31;
    const int kq = r >> 15;
    const int k  = kq * 64 + j2 * 2 + (w4 >> 1);
    const int g01 = w4 & 1;                               // 0:(i,f) 1:(g,o)
    const float f0 = W[((g01 * 2 + 0) * HH + u) * HH + k];
    const float f1 = W[((g01 * 2 + 1) * HH + u) * HH + k];
    WP[idx] = (unsigned int)f2bf(f0) | ((unsigned int)f2bf(f1) << 16);
}

// ---------- prep: WsbjT f32 [512][37] ----------
__global__ __launch_bounds__(256) void conv_wsbj(
    const float* __restrict__ Wsbj, float* __restrict__ WT)
{
    const int idx = blockIdx.x * 256 + threadIdx.x;
    if (idx >= 512 * KK) return;
    const int c = idx / KK, k = idx - c * KK;
    WT[idx] = Wsbj[k * 512 + c];
}

// ---------- GEMM 1: zin0 = gather(emb, text) @ Wih0^T + b0 (both dirs) ----------
__global__ __launch_bounds__(256) void gemm_embed(
    const int* __restrict__ text, const float* __restrict__ emb,
    const float* __restrict__ Wf, const float* __restrict__ bf_,
    const float* __restrict__ Wb, const float* __restrict__ bb_,
    unsigned short* __restrict__ zf, unsigned short* __restrict__ zb)
{
    const int dir = blockIdx.z;
    const float* W    = dir ? Wb  : Wf;
    const float* bias = dir ? bb_ : bf_;
    unsigned short* out = dir ? zb : zf;

    __shared__ float As[16][65];
    __shared__ float Bs[16][65];

    const int bm = blockIdx.x * 64;
    const int bn = blockIdx.y * 64;
    const int tid = threadIdx.x;
    const int ml = tid >> 2;
    const int kl = (tid & 3) * 4;

    const int r = bm + ml;
    const int t = r >> 6, b = r & 63;
    const int idx = text[b * TT + t];
    const float* arow = emb + idx * DD;
    const float* brow = W + (bn + ml) * DD;

    const int tx4 = (tid & 15) * 4, ty4 = (tid >> 4) * 4;
    float acc[4][4] = {};

    for (int kk = 0; kk < DD; kk += 16) {
        float4 av = make_float4(0.f, 0.f, 0.f, 0.f);
        float4 bv = make_float4(0.f, 0.f, 0.f, 0.f);
        const int d = kk + kl;
        if (d + 3 < DD) {
            av = *(const float4*)(arow + d);
            bv = *(const float4*)(brow + d);
        }
        As[kl + 0][ml] = av.x; As[kl + 1][ml] = av.y; As[kl + 2][ml] = av.z; As[kl + 3][ml] = av.w;
        Bs[kl + 0][ml] = bv.x; Bs[kl + 1][ml] = bv.y; Bs[kl + 2][ml] = bv.z; Bs[kl + 3][ml] = bv.w;
        __syncthreads();
        #pragma unroll
        for (int k = 0; k < 16; k++) {
            float a0 = As[k][ty4 + 0], a1 = As[k][ty4 + 1], a2 = As[k][ty4 + 2], a3 = As[k][ty4 + 3];
            float b0 = Bs[k][tx4 + 0], b1 = Bs[k][tx4 + 1], b2 = Bs[k][tx4 + 2], b3 = Bs[k][tx4 + 3];
            acc[0][0] += a0*b0; acc[0][1] += a0*b1; acc[0][2] += a0*b2; acc[0][3] += a0*b3;
            acc[1][0] += a1*b0; acc[1][1] += a1*b1; acc[1][2] += a1*b2; acc[1][3] += a1*b3;
            acc[2][0] += a2*b0; acc[2][1] += a2*b1; acc[2][2] += a2*b2; acc[2][3] += a2*b3;
            acc[3][0] += a3*b0; acc[3][1] += a3*b1; acc[3][2] += a3*b2; acc[3][3] += a3*b3;
        }
        __syncthreads();
    }
    #pragma unroll
    for (int i = 0; i < 4; i++) {
        const int rr = bm + ty4 + i;
        #pragma unroll
        for (int jj = 0; jj < 4; jj++) {
            const int nn = bn + tx4 + jj;
            out[rr * FH + perm_col(nn)] = f2bf(acc[i][jj] + bias[nn]);
        }
    }
}

// ---------- GEMM 2: zin1 = h0 @ Wih1^T + b1 (both dirs). A bf16, K=512 ----------
__global__ __launch_bounds__(256) void gemm_h(
    const unsigned short* __restrict__ h0,
    const float* __restrict__ Wf, const float* __restrict__ bf_,
    const float* __restrict__ Wb, const float* __restrict__ bb_,
    unsigned short* __restrict__ zf, unsigned short* __restrict__ zb)
{
    const int dir = blockIdx.z;
    const float* W    = dir ? Wb  : Wf;
    const float* bias = dir ? bb_ : bf_;
    unsigned short* out = dir ? zb : zf;

    __shared__ float As[16][65];
    __shared__ float Bs[16][65];

    const int bm = blockIdx.x * 64;
    const int bn = blockIdx.y * 64;
    const int tid = threadIdx.x;
    const int ml = tid >> 2;
    const int kl = (tid & 3) * 4;

    const unsigned short* arow = h0 + (bm + ml) * 512;
    const float* brow = W + (bn + ml) * 512;

    const int tx4 = (tid & 15) * 4, ty4 = (tid >> 4) * 4;
    float acc[4][4] = {};

    for (int kk = 0; kk < 512; kk += 16) {
        const int d = kk + kl;
        ushort4 av4 = *(const ushort4*)(arow + d);
        float4  bv  = *(const float4*)(brow + d);
        As[kl + 0][ml] = bf2f(av4.x); As[kl + 1][ml] = bf2f(av4.y);
        As[kl + 2][ml] = bf2f(av4.z); As[kl + 3][ml] = bf2f(av4.w);
        Bs[kl + 0][ml] = bv.x; Bs[kl + 1][ml] = bv.y; Bs[kl + 2][ml] = bv.z; Bs[kl + 3][ml] = bv.w;
        __syncthreads();
        #pragma unroll
        for (int k = 0; k < 16; k++) {
            float a0 = As[k][ty4 + 0], a1 = As[k][ty4 + 1], a2 = As[k][ty4 + 2], a3 = As[k][ty4 + 3];
            float b0 = Bs[k][tx4 + 0], b1 = Bs[k][tx4 + 1], b2 = Bs[k][tx4 + 2], b3 = Bs[k][tx4 + 3];
            acc[0][0] += a0*b0; acc[0][1] += a0*b1; acc[0][2] += a0*b2; acc[0][3] += a0*b3;
            acc[1][0] += a1*b0; acc[1][1] += a1*b1; acc[1][2] += a1*b2; acc[1][3] += a1*b3;
            acc[2][0] += a2*b0; acc[2][1] += a2*b1; acc[2][2] += a2*b2; acc[2][3] += a2*b3;
            acc[3][0] += a3*b0; acc[3][1] += a3*b1; acc[3][2] += a3*b2; acc[3][3] += a3*b3;
        }
        __syncthreads();
    }
    #pragma unroll
    for (int i = 0; i < 4; i++) {
        const int rr = bm + ty4 + i;
        #pragma unroll
        for (int jj = 0; jj < 4; jj++) {
            const int nn = bn + tx4 + jj;
            out[rr * FH + perm_col(nn)] = f2bf(acc[i][jj] + bias[nn]);
        }
    }
}

// ---------- LSTM recurrence: grid (64 batches, 2 dirs), 1024 threads ----------
// tid = kq*256 + u : thread accumulates 4 gates of unit u over k in [kq*64, kq*64+64).
// kq is wave-uniform -> LDS h reads are pure broadcast (conflict-free).
// Weights streamed as coalesced uint4 (2 k x 4 gates bf16) from the WP layout.
// Cross-kq reduce: float4 LDS write + 2 barriers/step.
// Per-CU/step: VALU ~4.9K cy (16 waves, 4/SIMD), weight stream 512 KB from L2.
__global__ __launch_bounds__(1024) void lstm_kernel(
    const unsigned short* __restrict__ zin_f, const unsigned short* __restrict__ zin_b,
    const unsigned int* __restrict__ WPf, const unsigned int* __restrict__ WPb,
    unsigned short* __restrict__ h_out)  // (T,B,512) bf16; fwd cols [0:256), bwd [256:512)
{
    const int dir = blockIdx.y;
    const unsigned short* zin = dir ? zin_b : zin_f;
    const unsigned int*   WP  = dir ? WPb : WPf;
    const int off = dir ? HH : 0;

    const int b = blockIdx.x;
    const int tid = threadIdx.x;
    const int u  = tid & 255;
    const int kq = tid >> 8;            // wave-uniform (waves 0-3:0, 4-7:1, ...)

    __shared__ float hs[2][HH];
    __shared__ float4 red[3][HH];
    if (tid < HH) hs[0][tid] = 0.0f;
    float c = 0.0f;
    int cur = 0;

    // uint4 stream base: uint4 index ((kq*32 + j2)*256 + u)
    const uint4* wp = (const uint4*)WP + (kq * 32) * 256 + u;

    __syncthreads();

    for (int ts = 0; ts < TT; ts++) {
        const int tt = dir ? (TT - 1 - ts) : ts;
        const int row = tt * BB + b;

        float ai = 0.f, af = 0.f, ag = 0.f, ao = 0.f;
        #pragma unroll 4
        for (int j4 = 0; j4 < 16; j4++) {
            const float4 hv = *(const float4*)&hs[cur][kq * 64 + j4 * 4];  // broadcast
            const uint4 wa = wp[(2 * j4 + 0) * 256];   // k+0,k+1
            const uint4 wb = wp[(2 * j4 + 1) * 256];   // k+2,k+3
            ai += bflo(wa.x) * hv.x; af += bfhi(wa.x) * hv.x;
            ag += bflo(wa.y) * hv.x; ao += bfhi(wa.y) * hv.x;
            ai += bflo(wa.z) * hv.y; af += bfhi(wa.z) * hv.y;
            ag += bflo(wa.w) * hv.y; ao += bfhi(wa.w) * hv.y;
            ai += bflo(wb.x) * hv.z; af += bfhi(wb.x) * hv.z;
            ag += bflo(wb.y) * hv.z; ao += bfhi(wb.y) * hv.z;
            ai += bflo(wb.z) * hv.w; af += bfhi(wb.z) * hv.w;
            ag += bflo(wb.w) * hv.w; ao += bfhi(wb.w) * hv.w;
        }

        if (kq) red[kq - 1][u] = make_float4(ai, af, ag, ao);
        __syncthreads();

        if (kq == 0) {
            const float4 r0 = red[0][u], r1 = red[1][u], r2 = red[2][u];
            const ushort4 zv = *(const ushort4*)(zin + row * FH + 4 * u);
            const float zi  = ai + r0.x + r1.x + r2.x + bf2f(zv.x);
            const float zf_ = af + r0.y + r1.y + r2.y + bf2f(zv.y);
            const float zg  = ag + r0.z + r1.z + r2.z + bf2f(zv.z);
            const float zo  = ao + r0.w + r1.w + r2.w + bf2f(zv.w);
            const float cc = sigm(zf_) * c + sigm(zi) * tanh_f(zg);
            c = cc;
            const float hh = sigm(zo) * tanh_f(cc);
            hs[cur ^ 1][u] = hh;
            h_out[row * (2 * HH) + off + u] = f2bf(hh);
        }
        __syncthreads();
        cur ^= 1;
    }
}

// ---------- Emission: em = h1 @ WsbjT + b_sbj, (MTOT,37) f32 ----------
__global__ __launch_bounds__(256) void em_kernel(
    const unsigned short* __restrict__ h1, const float* __restrict__ WsbjT,
    const float* __restrict__ bsbj, float* __restrict__ em)
{
    const int o = blockIdx.x * 256 + threadIdx.x;
    if (o >= MTOT * KK) return;
    const int r = o / KK, k = o - r * KK;
    const unsigned short* hr = h1 + r * 512;
    float s = bsbj[k];
    #pragma unroll 4
    for (int cidx = 0; cidx < 512; cidx++) {
        s += bf2f(hr[cidx]) * WsbjT[cidx * KK + k];
    }
    em[o] = s;
}

// ---------- CRF: one block (1 wave) per batch ----------
__global__ __launch_bounds__(64) void crf_kernel(
    const int* __restrict__ text, const int* __restrict__ sbj,
    const float* __restrict__ em,
    const float* __restrict__ start_t, const float* __restrict__ end_t,
    const float* __restrict__ trans, float* __restrict__ accum)
{
    const int b = blockIdx.x;
    const int tid = threadIdx.x;
    __shared__ float tr[KK * KK];
    __shared__ float sc[2][KK];
    for (int x = tid; x < KK * KK; x += 64) tr[x] = trans[x];

    int cnt = 0;
    for (int t = tid; t < TT; t += 64) cnt += (text[b * TT + t] != 0) ? 1 : 0;
    #pragma unroll
    for (int s = 32; s > 0; s >>= 1) cnt += __shfl_down(cnt, s, 64);
    const int len = __shfl(cnt, 0, 64);

    __syncthreads();

    float part = 0.f;
    for (int t = tid; t < TT; t += 64) {
        if (t >= 1 && t < len) {
            const int tg = sbj[b * TT + t];
            const int tp = sbj[b * TT + t - 1];
            part += em[(t * BB + b) * KK + tg] + tr[tp * KK + tg];
        }
    }
    #pragma unroll
    for (int s = 32; s > 0; s >>= 1) part += __shfl_down(part, s, 64);

    if (tid < KK) sc[0][tid] = start_t[tid] + em[b * KK + tid];
    __syncthreads();
    int cur = 0;
    for (int t = 1; t < len; t++) {
        float nv = 0.f;
        if (tid < KK) {
            float mx = -1e30f;
            for (int k1 = 0; k1 < KK; k1++)
                mx = fmaxf(mx, sc[cur][k1] + tr[k1 * KK + tid]);
            float s = 0.f;
            for (int k1 = 0; k1 < KK; k1++)
                s += __expf(sc[cur][k1] + tr[k1 * KK + tid] - mx);
            nv = mx + __logf(s) + em[(t * BB + b) * KK + tid];
        }
        if (tid < KK) sc[cur ^ 1][tid] = nv;
        __syncthreads();
        cur ^= 1;
    }

    if (tid == 0) {
        const int tg0 = sbj[b * TT];
        const int tgl = sbj[b * TT + len - 1];
        const float num = start_t[tg0] + em[b * KK + tg0] + part + end_t[tgl];
        float mx = -1e30f;
        for (int k = 0; k < KK; k++) mx = fmaxf(mx, sc[cur][k] + end_t[k]);
        float s = 0.f;
        for (int k = 0; k < KK; k++) s += __expf(sc[cur][k] + end_t[k] - mx);
        const float logZ = mx + __logf(s);
        atomicAdd(&accum[0], num - logZ);
        atomicAdd(&accum[1], (float)len);
    }
}

__global__ void init_kernel(float* __restrict__ accum) {
    if (threadIdx.x < 2) accum[threadIdx.x] = 0.0f;
}
__global__ void final_kernel(const float* __restrict__ accum, float* __restrict__ out) {
    out[0] = -(accum[0] / accum[1]);
}

// ---------- launch ----------
extern "C" void kernel_launch(void* const* d_in, const int* in_sizes, int n_in,
                              void* d_out, int out_size, void* d_ws, size_t ws_size,
                              hipStream_t stream)
{
    (void)in_sizes; (void)n_in; (void)out_size; (void)ws_size;
    const int*   text  = (const int*)d_in[0];
    const int*   sbj   = (const int*)d_in[1];
    const float* emb   = (const float*)d_in[2];
    const float* Wih0f = (const float*)d_in[3];
    const float* Whh0f = (const float*)d_in[4];
    const float* b0f   = (const float*)d_in[5];
    const float* Wih0b = (const float*)d_in[6];
    const float* Whh0b = (const float*)d_in[7];
    const float* b0b   = (const float*)d_in[8];
    const float* Wih1f = (const float*)d_in[9];
    const float* Whh1f = (const float*)d_in[10];
    const float* b1f   = (const float*)d_in[11];
    const float* Wih1b = (const float*)d_in[12];
    const float* Whh1b = (const float*)d_in[13];
    const float* b1b   = (const float*)d_in[14];
    const float* Wsbj  = (const float*)d_in[15];
    const float* bsbj  = (const float*)d_in[16];
    const float* start_t = (const float*)d_in[17];
    const float* end_t   = (const float*)d_in[18];
    const float* trans   = (const float*)d_in[19];

    // workspace map (bytes), max ~102.8 MiB (em overlaps dead zf region)
    char* ws = (char*)d_ws;
    unsigned short* zf   = (unsigned short*)(ws + 0);           // 32 MiB
    unsigned short* zb   = (unsigned short*)(ws + 33554432);    // 32 MiB
    unsigned short* h0   = (unsigned short*)(ws + 67108864);    // 16 MiB
    unsigned short* h1   = (unsigned short*)(ws + 83886080);    // 16 MiB
    unsigned int*   WP   = (unsigned int*)(ws + 100663296);     // 4 x 512 KiB
    float*        WsbjT  = (float*)(ws + 102760448);            // 76 KiB
    float*          acc  = (float*)(ws + 102836224);            // 8 B
    float*           em  = (float*)(ws + 0);                    // 2.4 MiB, reuses zf
    float* out = (float*)d_out;

    unsigned int* WP0f = WP + 0 * 131072;
    unsigned int* WP0b = WP + 1 * 131072;
    unsigned int* WP1f = WP + 2 * 131072;
    unsigned int* WP1b = WP + 3 * 131072;

    init_kernel<<<1, 64, 0, stream>>>(acc);
    conv_whh<<<dim3(2048), 256, 0, stream>>>(Whh0f, Whh0b, Whh1f, Whh1b, WP);
    conv_wsbj<<<dim3(74), 256, 0, stream>>>(Wsbj, WsbjT);

    gemm_embed<<<dim3(256, 16, 2), 256, 0, stream>>>(text, emb, Wih0f, b0f, Wih0b, b0b, zf, zb);
    lstm_kernel<<<dim3(BB, 2), 1024, 0, stream>>>(zf, zb, WP0f, WP0b, h0);
    gemm_h<<<dim3(256, 16, 2), 256, 0, stream>>>(h0, Wih1f, b1f, Wih1b, b1b, zf, zb);
    lstm_kernel<<<dim3(BB, 2), 1024, 0, stream>>>(zf, zb, WP1f, WP1b, h1);
    em_kernel<<<(MTOT * KK + 255) / 256, 256, 0, stream>>>(h1, WsbjT, bsbj, em);
    crf_kernel<<<BB, 64, 0, stream>>>(text, sbj, em, start_t, end_t, trans, acc);
    final_kernel<<<1, 1, 0, stream>>>(acc, out);
}